// Round 10
// baseline (97.021 us; speedup 1.0000x reference)
//
#include <hip/hip_runtime.h>
#include <hip/hip_bf16.h>

#define N 4096
#define D 768
#define NC 6    // D/128 K-chunks per gemm pass

typedef float f32x4 __attribute__((ext_vector_type(4)));
typedef int v8i __attribute__((ext_vector_type(8)));

typedef __attribute__((address_space(3))) unsigned int as3_uint;
typedef const __attribute__((address_space(1))) unsigned int as1_uint;

__device__ __forceinline__ void gload16(const void* g, void* l) {
    __builtin_amdgcn_global_load_lds((as1_uint*)g, (as3_uint*)l, 16, 0, 0);
}

// Tiled fp8 global layout for mfma_scale_f32_16x16x128_f8f6f4 (R7-verified):
// frag-tile = 16 rows x 128 k = 2048B, tile index (R>>4)*6 + (k>>7).
// Within a tile: lane l = (R&15) + 16*((k&127)>>5) holds 32 contiguous k,
// stored as two lane-linear 1024B halves (byte = half*1024 + l*16 + (k&15)).
// -> operand = two 16B loads at p and p+1024 (global or LDS, conflict-free).

// ---------------- normalize: f32 [N][D] -> fp8 tiled, row L2-normalized ------
__global__ __launch_bounds__(256) void norm4(const float* __restrict__ x0,
                                             const float* __restrict__ x1,
                                             const float* __restrict__ x2,
                                             const float* __restrict__ x3,
                                             unsigned char* __restrict__ o) {
    int a = blockIdx.y;
    const float* x = (a == 0) ? x0 : (a == 1) ? x1 : (a == 2) ? x2 : x3;
    unsigned char* out = o + (size_t)a * N * D;
    int i0 = blockIdx.x * 32;                 // 32-row group
    __shared__ __align__(16) unsigned char tile[24576];
    int t = threadIdx.x, lane = t & 63, w = t >> 6;

    for (int rr = 0; rr < 8; ++rr) {
        int R = i0 + w * 8 + rr;
        const f32x4* xr = (const f32x4*)(x + (size_t)R * D);
        f32x4 v0 = xr[lane * 2], v1 = xr[lane * 2 + 1];
        f32x4 v2 = {}, v3 = {};
        if (lane < 32) { v2 = xr[128 + lane * 2]; v3 = xr[128 + lane * 2 + 1]; }
        float ss = v0[0]*v0[0] + v0[1]*v0[1] + v0[2]*v0[2] + v0[3]*v0[3]
                 + v1[0]*v1[0] + v1[1]*v1[1] + v1[2]*v1[2] + v1[3]*v1[3]
                 + v2[0]*v2[0] + v2[1]*v2[1] + v2[2]*v2[2] + v2[3]*v2[3]
                 + v3[0]*v3[0] + v3[1]*v3[1] + v3[2]*v3[2] + v3[3]*v3[3];
        #pragma unroll
        for (int m = 1; m < 64; m <<= 1) ss += __shfl_xor(ss, m);
        float s = 1.0f / fmaxf(sqrtf(ss), 1e-8f);

        int lrg = (R >> 4) & 1;
        {
            unsigned int wlo = __builtin_amdgcn_cvt_pk_fp8_f32(v0[0]*s, v0[1]*s, 0, false) & 0xffff;
            unsigned int whi = __builtin_amdgcn_cvt_pk_fp8_f32(v0[2]*s, v0[3]*s, 0, false) & 0xffff;
            unsigned int w0 = wlo | (whi << 16);
            wlo = __builtin_amdgcn_cvt_pk_fp8_f32(v1[0]*s, v1[1]*s, 0, false) & 0xffff;
            whi = __builtin_amdgcn_cvt_pk_fp8_f32(v1[2]*s, v1[3]*s, 0, false) & 0xffff;
            unsigned int w1 = wlo | (whi << 16);
            int g = lane;
            int off = (lrg * 6 + (g >> 4)) * 2048 + ((g >> 1) & 1) * 1024
                    + ((R & 15) + 16 * ((g & 15) >> 2)) * 16 + (g & 1) * 8;
            *(uint2*)(tile + off) = make_uint2(w0, w1);
        }
        if (lane < 32) {
            unsigned int wlo = __builtin_amdgcn_cvt_pk_fp8_f32(v2[0]*s, v2[1]*s, 0, false) & 0xffff;
            unsigned int whi = __builtin_amdgcn_cvt_pk_fp8_f32(v2[2]*s, v2[3]*s, 0, false) & 0xffff;
            unsigned int w0 = wlo | (whi << 16);
            wlo = __builtin_amdgcn_cvt_pk_fp8_f32(v3[0]*s, v3[1]*s, 0, false) & 0xffff;
            whi = __builtin_amdgcn_cvt_pk_fp8_f32(v3[2]*s, v3[3]*s, 0, false) & 0xffff;
            unsigned int w1 = wlo | (whi << 16);
            int g = 64 + lane;
            int off = (lrg * 6 + (g >> 4)) * 2048 + ((g >> 1) & 1) * 1024
                    + ((R & 15) + 16 * ((g & 15) >> 2)) * 16 + (g & 1) * 8;
            *(uint2*)(tile + off) = make_uint2(w0, w1);
        }
    }
    __syncthreads();
    unsigned char* dst = out + (size_t)(i0 >> 5) * 24576;
    #pragma unroll
    for (int i = 0; i < 6; ++i)
        ((int4*)dst)[t + i * 256] = ((const int4*)tile)[t + i * 256];
}

// ---------------- one gemm pass: acc += A_blk(128) x B_blk(128)^T ------------
// SINGLE-buffered 32KB LDS (A 8 frag-tiles @0, B @16384) -> 4 blocks/CU;
// cross-block wave overlap hides the per-chunk stage latency (m97/m114
// precedent). Per chunk: 8 gloads -> vmcnt(0) -> barrier -> 16 ds_read_b128
// -> 16 MFMA(K=128, scales=1) -> barrier.
__device__ __forceinline__ void gemm_pass(const unsigned char* __restrict__ A,
                                          const unsigned char* __restrict__ B,
                                          char* smem, int ib, int jb, int t,
                                          f32x4 (&acc)[4][4]) {
    const int lane = t & 63, w = t >> 6;
    const int wm = w >> 1, wn = w & 1;

    // staging: wave w covers A frag-tiles {2w, 2w+1}, B frag-tiles {2w, 2w+1}
    const unsigned char* gA = A + (size_t)((ib * 8 + 2 * w) * 6) * 2048 + lane * 16;
    const unsigned char* gB = B + (size_t)((jb * 8 + 2 * w) * 6) * 2048 + lane * 16;
    const int sd = w * 4096 + lane * 16;

    #pragma unroll 1
    for (int c = 0; c < NC; ++c) {
        const unsigned char* sa = gA + c * 2048;
        const unsigned char* sb = gB + c * 2048;
        gload16(sa,         smem + sd);
        gload16(sa + 1024,  smem + sd + 1024);
        gload16(sa + 12288, smem + sd + 2048);   // tile 2w+1 (6 chunks ahead)
        gload16(sa + 13312, smem + sd + 3072);
        gload16(sb,         smem + 16384 + sd);
        gload16(sb + 1024,  smem + 16384 + sd + 1024);
        gload16(sb + 12288, smem + 16384 + sd + 2048);
        gload16(sb + 13312, smem + 16384 + sd + 3072);

        asm volatile("s_waitcnt vmcnt(0)" ::: "memory");
        __builtin_amdgcn_s_barrier();
        asm volatile("" ::: "memory");

        union { int4 q[2]; v8i v; } a[4], b[4];
        #pragma unroll
        for (int m = 0; m < 4; ++m) {
            const char* p = smem + (wm * 4 + m) * 2048 + lane * 16;
            a[m].q[0] = *(const int4*)p;
            a[m].q[1] = *(const int4*)(p + 1024);
        }
        #pragma unroll
        for (int n = 0; n < 4; ++n) {
            const char* p = smem + 16384 + (wn * 4 + n) * 2048 + lane * 16;
            b[n].q[0] = *(const int4*)p;
            b[n].q[1] = *(const int4*)(p + 1024);
        }
        __builtin_amdgcn_s_setprio(1);
        #pragma unroll
        for (int m = 0; m < 4; ++m)
            #pragma unroll
            for (int n = 0; n < 4; ++n)
                acc[m][n] = __builtin_amdgcn_mfma_scale_f32_16x16x128_f8f6f4(
                    a[m].v, b[n].v, acc[m][n], 0, 0, 0, 127, 0, 127);
        __builtin_amdgcn_s_setprio(0);
        __builtin_amdgcn_s_barrier();   // all reads of this buffer done
    }
}

__global__ __launch_bounds__(256, 4) void fused_gemm(
        const unsigned char* __restrict__ Xs, const unsigned char* __restrict__ Ys,
        const unsigned char* __restrict__ Xt, const unsigned char* __restrict__ Yt,
        float* __restrict__ partial) {
    __shared__ __align__(16) char smem[32768];
    const int t = threadIdx.x;
    const int jb = blockIdx.x, ib = blockIdx.y;
    const int i0 = ib * 128;
    const int lane = t & 63, wid = t >> 6;
    const int wm = wid >> 1, wn = wid & 1;

    f32x4 acc_s[4][4] = {};
    f32x4 acc_t[4][4] = {};

    gemm_pass(Xs, Ys, smem, ib, jb, t, acc_s);
    gemm_pass(Xt, Yt, smem, ib, jb, t, acc_t);

    // ---- epilogue (R5-proven): per-row partials over this block's 128 cols --
    __syncthreads();
    float* part = (float*)smem;      // [2 wn][128 rows][4 stats]
    int g = lane >> 4, cl = lane & 15;

    #pragma unroll
    for (int m = 0; m < 4; ++m) {
        float st[4][4];
        #pragma unroll
        for (int r = 0; r < 4; ++r) { st[r][0] = 0.f; st[r][1] = 0.f; st[r][2] = 0.f; st[r][3] = 0.f; }
        #pragma unroll
        for (int n = 0; n < 4; ++n)
            #pragma unroll
            for (int r = 0; r < 4; ++r) {
                float ls = 10.0f * acc_s[m][n][r];
                float lt = 10.0f * acc_t[m][n][r];
                float es = __expf(ls - 10.0f);
                float et = __expf(lt - 10.0f);
                st[r][0] += es;
                st[r][1] += et;
                st[r][2] += es * (ls - lt);
                st[r][3] += et * (lt - ls);
            }
        #pragma unroll
        for (int r = 0; r < 4; ++r)
            #pragma unroll
            for (int s = 0; s < 4; ++s) {
                float v = st[r][s];
                v += __shfl_xor(v, 1);
                v += __shfl_xor(v, 2);
                v += __shfl_xor(v, 4);
                v += __shfl_xor(v, 8);
                st[r][s] = v;
            }
        if (cl == 0) {
            int row = wm * 64 + m * 16 + g * 4;
            #pragma unroll
            for (int r = 0; r < 4; ++r)
                #pragma unroll
                for (int s = 0; s < 4; ++s)
                    part[(wn * 128 + row + r) * 4 + s] = st[r][s];
        }
    }
    __syncthreads();
    #pragma unroll
    for (int q = 0; q < 2; ++q) {
        int idx = t + q * 256;
        int row = idx >> 2, s = idx & 3;
        float v = part[(0 * 128 + row) * 4 + s] + part[(1 * 128 + row) * 4 + s];
        partial[((size_t)jb * N + (i0 + row)) * 4 + s] = v;
    }
}

// ---------------- per-row finalize + block partial sums ----------------------
__global__ __launch_bounds__(256) void reduce_rows(const float* __restrict__ partial,
                                                   float* __restrict__ blocksum) {
    int row = blockIdx.x * 256 + threadIdx.x;
    float zs = 0.f, zt = 0.f, ws = 0.f, wt = 0.f;
    for (int jb = 0; jb < 32; ++jb) {
        const float* p = partial + ((size_t)jb * N + row) * 4;
        zs += p[0]; zt += p[1]; ws += p[2]; wt += p[3];
    }
    float ls_row = wt / zt - logf(zt) + logf(zs);
    float lt_row = ws / zs - logf(zs) + logf(zt);
    #pragma unroll
    for (int m = 1; m < 64; m <<= 1) {
        ls_row += __shfl_xor(ls_row, m);
        lt_row += __shfl_xor(lt_row, m);
    }
    __shared__ float rs[4], rt[4];
    int lane = threadIdx.x & 63, wid = threadIdx.x >> 6;
    if (lane == 0) { rs[wid] = ls_row; rt[wid] = lt_row; }
    __syncthreads();
    if (threadIdx.x == 0) {
        blocksum[blockIdx.x * 2]     = rs[0] + rs[1] + rs[2] + rs[3];
        blocksum[blockIdx.x * 2 + 1] = rt[0] + rt[1] + rt[2] + rt[3];
    }
}

__global__ void final_reduce(const float* __restrict__ blocksum, float* __restrict__ out) {
    float a = 0.f, b = 0.f;
    if (threadIdx.x < 16) { a = blocksum[threadIdx.x * 2]; b = blocksum[threadIdx.x * 2 + 1]; }
    #pragma unroll
    for (int m = 1; m < 16; m <<= 1) { a += __shfl_xor(a, m); b += __shfl_xor(b, m); }
    if (threadIdx.x == 0) {
        const float inv = 1.0f / 16777216.0f;   // 1/N^2
        out[0] = a * inv;
        out[1] = b * inv;
    }
}

extern "C" void kernel_launch(void* const* d_in, const int* in_sizes, int n_in,
                              void* d_out, int out_size, void* d_ws, size_t ws_size,
                              hipStream_t stream) {
    const float* zxs = (const float*)d_in[0];
    const float* zys = (const float*)d_in[1];
    const float* zxt = (const float*)d_in[2];
    const float* zyt = (const float*)d_in[3];

    char* ws = (char*)d_ws;
    const size_t A = (size_t)N * D;                   // bytes per fp8 array
    unsigned char* nb = (unsigned char*)ws;           // 4 normalized fp8 arrays (tiled)
    float* partial  = (float*)(ws + 4 * A);           // [32][N][4] f32 = 2 MB
    float* blocksum = (float*)(ws + 4 * A + (size_t)32 * N * 4 * sizeof(float));

    norm4<<<dim3(N / 32, 4), 256, 0, stream>>>(zxs, zys, zxt, zyt, nb);

    const unsigned char* Xs = nb;
    const unsigned char* Ys = nb + A;
    const unsigned char* Xt = nb + 2 * A;
    const unsigned char* Yt = nb + 3 * A;
    fused_gemm<<<dim3(32, 32), 256, 0, stream>>>(Xs, Ys, Xt, Yt, partial);

    reduce_rows<<<16, 256, 0, stream>>>(partial, blocksum);
    final_reduce<<<1, 64, 0, stream>>>(blocksum, (float*)d_out);
}

// Round 11
// 71.190 us; speedup vs baseline: 1.3628x; 1.3628x over previous
//
#include <hip/hip_runtime.h>
#include <hip/hip_bf16.h>

#define N 4096
#define D 768
#define NC 6    // D/128 K-chunks per gemm pass

typedef float f32x4 __attribute__((ext_vector_type(4)));
typedef int v8i __attribute__((ext_vector_type(8)));

typedef __attribute__((address_space(3))) unsigned int as3_uint;
typedef const __attribute__((address_space(1))) unsigned int as1_uint;

__device__ __forceinline__ void gload16(const void* g, void* l) {
    __builtin_amdgcn_global_load_lds((as1_uint*)g, (as3_uint*)l, 16, 0, 0);
}

// Tiled fp8 global layout for mfma_scale_f32_16x16x128_f8f6f4 (R7-verified):
// frag-tile = 16 rows x 128 k = 2048B, tile index (R>>4)*6 + (k>>7).
// Within a tile: lane l = (R&15) + 16*((k&127)>>5) holds 32 contiguous k,
// stored as two lane-linear 1024B halves (byte = half*1024 + l*16 + (k&15)).
// -> operand = two 16B loads at p and p+1024 (global or LDS, conflict-free).

// ---------------- normalize: f32 [N][D] -> fp8 tiled, row L2-normalized ------
__global__ __launch_bounds__(256) void norm4(const float* __restrict__ x0,
                                             const float* __restrict__ x1,
                                             const float* __restrict__ x2,
                                             const float* __restrict__ x3,
                                             unsigned char* __restrict__ o) {
    int a = blockIdx.y;
    const float* x = (a == 0) ? x0 : (a == 1) ? x1 : (a == 2) ? x2 : x3;
    unsigned char* out = o + (size_t)a * N * D;
    int i0 = blockIdx.x * 32;                 // 32-row group
    __shared__ __align__(16) unsigned char tile[24576];
    int t = threadIdx.x, lane = t & 63, w = t >> 6;

    for (int rr = 0; rr < 8; ++rr) {
        int R = i0 + w * 8 + rr;
        const f32x4* xr = (const f32x4*)(x + (size_t)R * D);
        f32x4 v0 = xr[lane * 2], v1 = xr[lane * 2 + 1];
        f32x4 v2 = {}, v3 = {};
        if (lane < 32) { v2 = xr[128 + lane * 2]; v3 = xr[128 + lane * 2 + 1]; }
        float ss = v0[0]*v0[0] + v0[1]*v0[1] + v0[2]*v0[2] + v0[3]*v0[3]
                 + v1[0]*v1[0] + v1[1]*v1[1] + v1[2]*v1[2] + v1[3]*v1[3]
                 + v2[0]*v2[0] + v2[1]*v2[1] + v2[2]*v2[2] + v2[3]*v2[3]
                 + v3[0]*v3[0] + v3[1]*v3[1] + v3[2]*v3[2] + v3[3]*v3[3];
        #pragma unroll
        for (int m = 1; m < 64; m <<= 1) ss += __shfl_xor(ss, m);
        float s = 1.0f / fmaxf(sqrtf(ss), 1e-8f);

        int lrg = (R >> 4) & 1;
        {
            unsigned int wlo = __builtin_amdgcn_cvt_pk_fp8_f32(v0[0]*s, v0[1]*s, 0, false) & 0xffff;
            unsigned int whi = __builtin_amdgcn_cvt_pk_fp8_f32(v0[2]*s, v0[3]*s, 0, false) & 0xffff;
            unsigned int w0 = wlo | (whi << 16);
            wlo = __builtin_amdgcn_cvt_pk_fp8_f32(v1[0]*s, v1[1]*s, 0, false) & 0xffff;
            whi = __builtin_amdgcn_cvt_pk_fp8_f32(v1[2]*s, v1[3]*s, 0, false) & 0xffff;
            unsigned int w1 = wlo | (whi << 16);
            int g = lane;
            int off = (lrg * 6 + (g >> 4)) * 2048 + ((g >> 1) & 1) * 1024
                    + ((R & 15) + 16 * ((g & 15) >> 2)) * 16 + (g & 1) * 8;
            *(uint2*)(tile + off) = make_uint2(w0, w1);
        }
        if (lane < 32) {
            unsigned int wlo = __builtin_amdgcn_cvt_pk_fp8_f32(v2[0]*s, v2[1]*s, 0, false) & 0xffff;
            unsigned int whi = __builtin_amdgcn_cvt_pk_fp8_f32(v2[2]*s, v2[3]*s, 0, false) & 0xffff;
            unsigned int w0 = wlo | (whi << 16);
            wlo = __builtin_amdgcn_cvt_pk_fp8_f32(v3[0]*s, v3[1]*s, 0, false) & 0xffff;
            whi = __builtin_amdgcn_cvt_pk_fp8_f32(v3[2]*s, v3[3]*s, 0, false) & 0xffff;
            unsigned int w1 = wlo | (whi << 16);
            int g = 64 + lane;
            int off = (lrg * 6 + (g >> 4)) * 2048 + ((g >> 1) & 1) * 1024
                    + ((R & 15) + 16 * ((g & 15) >> 2)) * 16 + (g & 1) * 8;
            *(uint2*)(tile + off) = make_uint2(w0, w1);
        }
    }
    __syncthreads();
    unsigned char* dst = out + (size_t)(i0 >> 5) * 24576;
    #pragma unroll
    for (int i = 0; i < 6; ++i)
        ((int4*)dst)[t + i * 256] = ((const int4*)tile)[t + i * 256];
}

// ---------------- one gemm pass: acc += A_blk(128) x B_blk(128)^T ------------
// 512 threads / 8 waves (2 wm x 4 wn), wave tile 64x32 per gemm -> acc only
// 8 f32x4/thread/gemm. LDS buffer 32KB (A 8 frag-tiles @0, B @16384), dbuf
// 64KB -> 2 blocks/CU = 16 waves/CU = 4 waves/SIMD (2x R7 TLP).
// R7-verified schedule: ISSUE(c+1) -> counted vmcnt(4) -> barrier -> ds_read
// -> MFMA(K=128, scales=1) -> barrier. Never drains vmcnt in loop.
__device__ __forceinline__ void gemm_pass(const unsigned char* __restrict__ A,
                                          const unsigned char* __restrict__ B,
                                          char* smem, int ib, int jb, int t,
                                          f32x4 (&acc)[4][2]) {
    const int lane = t & 63, w = t >> 6;     // w 0..7
    const int wm = w >> 2, wn = w & 3;

    // staging: thread t covers A tiles {t>>7, 4+(t>>7)}, B same, 16B granule
    const int stile = t >> 7;                // 0..3
    const int sbyte = (t & 127) * 16;
    const unsigned char* gA0 = A + (size_t)((ib * 8 + stile) * 6) * 2048 + sbyte;
    const unsigned char* gA1 = A + (size_t)((ib * 8 + 4 + stile) * 6) * 2048 + sbyte;
    const unsigned char* gB0 = B + (size_t)((jb * 8 + stile) * 6) * 2048 + sbyte;
    const unsigned char* gB1 = B + (size_t)((jb * 8 + 4 + stile) * 6) * 2048 + sbyte;
    const int sd = t * 16;                   // lane-linear LDS dest

    #define ISSUE(c) do {                                                      \
        char* buf = smem + ((c) & 1) * 32768;                                  \
        gload16(gA0 + (c) * 2048, buf + sd);                                   \
        gload16(gA1 + (c) * 2048, buf + 8192 + sd);                            \
        gload16(gB0 + (c) * 2048, buf + 16384 + sd);                           \
        gload16(gB1 + (c) * 2048, buf + 24576 + sd);                           \
    } while (0)

    ISSUE(0);

    #pragma unroll 1
    for (int c = 0; c < NC; ++c) {
        if (c < NC - 1) {
            ISSUE(c + 1);
            asm volatile("s_waitcnt vmcnt(4)" ::: "memory");  // c staged, c+1 in flight
        } else {
            asm volatile("s_waitcnt vmcnt(0)" ::: "memory");
        }
        __builtin_amdgcn_s_barrier();
        asm volatile("" ::: "memory");

        const char* cb = smem + (c & 1) * 32768;
        union { int4 q[2]; v8i v; } a[4], b[2];
        #pragma unroll
        for (int m = 0; m < 4; ++m) {
            const char* p = cb + (wm * 4 + m) * 2048 + lane * 16;
            a[m].q[0] = *(const int4*)p;
            a[m].q[1] = *(const int4*)(p + 1024);
        }
        #pragma unroll
        for (int n = 0; n < 2; ++n) {
            const char* p = cb + 16384 + (wn * 2 + n) * 2048 + lane * 16;
            b[n].q[0] = *(const int4*)p;
            b[n].q[1] = *(const int4*)(p + 1024);
        }
        __builtin_amdgcn_s_setprio(1);
        #pragma unroll
        for (int m = 0; m < 4; ++m)
            #pragma unroll
            for (int n = 0; n < 2; ++n)
                acc[m][n] = __builtin_amdgcn_mfma_scale_f32_16x16x128_f8f6f4(
                    a[m].v, b[n].v, acc[m][n], 0, 0, 0, 127, 0, 127);
        __builtin_amdgcn_s_setprio(0);
        __builtin_amdgcn_s_barrier();    // all reads of buf c done before restage
    }
    #undef ISSUE
}

__global__ __launch_bounds__(512, 4) void fused_gemm(
        const unsigned char* __restrict__ Xs, const unsigned char* __restrict__ Ys,
        const unsigned char* __restrict__ Xt, const unsigned char* __restrict__ Yt,
        float* __restrict__ partial) {
    __shared__ __align__(16) char smem[65536];
    const int t = threadIdx.x;
    const int jb = blockIdx.x, ib = blockIdx.y;
    const int i0 = ib * 128;
    const int lane = t & 63, wid = t >> 6;
    const int wm = wid >> 2, wn = wid & 3;

    f32x4 acc_s[4][2] = {};
    f32x4 acc_t[4][2] = {};

    gemm_pass(Xs, Ys, smem, ib, jb, t, acc_s);
    gemm_pass(Xt, Yt, smem, ib, jb, t, acc_t);

    // ---- epilogue: per-row partial stats over this block's 128 columns ----
    __syncthreads();
    float* part = (float*)smem;      // [4 wn][128 rows][4 stats] = 8KB
    int g = lane >> 4, cl = lane & 15;

    #pragma unroll
    for (int m = 0; m < 4; ++m) {
        float st[4][4];
        #pragma unroll
        for (int r = 0; r < 4; ++r) { st[r][0] = 0.f; st[r][1] = 0.f; st[r][2] = 0.f; st[r][3] = 0.f; }
        #pragma unroll
        for (int n = 0; n < 2; ++n)
            #pragma unroll
            for (int r = 0; r < 4; ++r) {
                float ls = 10.0f * acc_s[m][n][r];
                float lt = 10.0f * acc_t[m][n][r];
                float es = __expf(ls - 10.0f);
                float et = __expf(lt - 10.0f);
                st[r][0] += es;
                st[r][1] += et;
                st[r][2] += es * (ls - lt);
                st[r][3] += et * (lt - ls);
            }
        #pragma unroll
        for (int r = 0; r < 4; ++r)
            #pragma unroll
            for (int s = 0; s < 4; ++s) {
                float v = st[r][s];
                v += __shfl_xor(v, 1);
                v += __shfl_xor(v, 2);
                v += __shfl_xor(v, 4);
                v += __shfl_xor(v, 8);
                st[r][s] = v;
            }
        if (cl == 0) {
            int row = wm * 64 + m * 16 + g * 4;
            #pragma unroll
            for (int r = 0; r < 4; ++r)
                #pragma unroll
                for (int s = 0; s < 4; ++s)
                    part[(wn * 128 + row + r) * 4 + s] = st[r][s];
        }
    }
    __syncthreads();
    {
        int row = t >> 2, s = t & 3;     // 512 slots = 128 rows x 4 stats
        float v = part[(0 * 128 + row) * 4 + s] + part[(1 * 128 + row) * 4 + s]
                + part[(2 * 128 + row) * 4 + s] + part[(3 * 128 + row) * 4 + s];
        partial[((size_t)jb * N + (i0 + row)) * 4 + s] = v;
    }
}

// ---------------- per-row finalize + block partial sums ----------------------
__global__ __launch_bounds__(256) void reduce_rows(const float* __restrict__ partial,
                                                   float* __restrict__ blocksum) {
    int row = blockIdx.x * 256 + threadIdx.x;
    float zs = 0.f, zt = 0.f, ws = 0.f, wt = 0.f;
    for (int jb = 0; jb < 32; ++jb) {
        const float* p = partial + ((size_t)jb * N + row) * 4;
        zs += p[0]; zt += p[1]; ws += p[2]; wt += p[3];
    }
    float ls_row = wt / zt - logf(zt) + logf(zs);
    float lt_row = ws / zs - logf(zs) + logf(zt);
    #pragma unroll
    for (int m = 1; m < 64; m <<= 1) {
        ls_row += __shfl_xor(ls_row, m);
        lt_row += __shfl_xor(lt_row, m);
    }
    __shared__ float rs[4], rt[4];
    int lane = threadIdx.x & 63, wid = threadIdx.x >> 6;
    if (lane == 0) { rs[wid] = ls_row; rt[wid] = lt_row; }
    __syncthreads();
    if (threadIdx.x == 0) {
        blocksum[blockIdx.x * 2]     = rs[0] + rs[1] + rs[2] + rs[3];
        blocksum[blockIdx.x * 2 + 1] = rt[0] + rt[1] + rt[2] + rt[3];
    }
}

__global__ void final_reduce(const float* __restrict__ blocksum, float* __restrict__ out) {
    float a = 0.f, b = 0.f;
    if (threadIdx.x < 16) { a = blocksum[threadIdx.x * 2]; b = blocksum[threadIdx.x * 2 + 1]; }
    #pragma unroll
    for (int m = 1; m < 16; m <<= 1) { a += __shfl_xor(a, m); b += __shfl_xor(b, m); }
    if (threadIdx.x == 0) {
        const float inv = 1.0f / 16777216.0f;   // 1/N^2
        out[0] = a * inv;
        out[1] = b * inv;
    }
}

extern "C" void kernel_launch(void* const* d_in, const int* in_sizes, int n_in,
                              void* d_out, int out_size, void* d_ws, size_t ws_size,
                              hipStream_t stream) {
    const float* zxs = (const float*)d_in[0];
    const float* zys = (const float*)d_in[1];
    const float* zxt = (const float*)d_in[2];
    const float* zyt = (const float*)d_in[3];

    char* ws = (char*)d_ws;
    const size_t A = (size_t)N * D;                   // bytes per fp8 array
    unsigned char* nb = (unsigned char*)ws;           // 4 normalized fp8 arrays (tiled)
    float* partial  = (float*)(ws + 4 * A);           // [32][N][4] f32 = 2 MB
    float* blocksum = (float*)(ws + 4 * A + (size_t)32 * N * 4 * sizeof(float));

    norm4<<<dim3(N / 32, 4), 256, 0, stream>>>(zxs, zys, zxt, zyt, nb);

    const unsigned char* Xs = nb;
    const unsigned char* Ys = nb + A;
    const unsigned char* Xt = nb + 2 * A;
    const unsigned char* Yt = nb + 3 * A;
    fused_gemm<<<dim3(32, 32), 512, 0, stream>>>(Xs, Ys, Xt, Yt, partial);

    reduce_rows<<<16, 256, 0, stream>>>(partial, blocksum);
    final_reduce<<<1, 64, 0, stream>>>(blocksum, (float*)d_out);
}

// Round 12
// 61.087 us; speedup vs baseline: 1.5882x; 1.1654x over previous
//
#include <hip/hip_runtime.h>
#include <hip/hip_bf16.h>

#define N 4096
#define D 768
#define NC 6    // D/128 K-chunks per gemm pass

typedef float f32x4 __attribute__((ext_vector_type(4)));
typedef int v8i __attribute__((ext_vector_type(8)));

typedef __attribute__((address_space(3))) unsigned int as3_uint;
typedef const __attribute__((address_space(1))) unsigned int as1_uint;

__device__ __forceinline__ void gload16(const void* g, void* l) {
    __builtin_amdgcn_global_load_lds((as1_uint*)g, (as3_uint*)l, 16, 0, 0);
}

// Tiled fp8 global layout for mfma_scale_f32_16x16x128_f8f6f4 (R7-verified):
// frag-tile = 16 rows x 128 k = 2048B, tile index (R>>4)*6 + (k>>7).
// Within a tile: lane l = (R&15) + 16*((k&127)>>5) holds 32 contiguous k,
// stored as two lane-linear 1024B halves (byte = half*1024 + l*16 + (k&15)).
// -> operand = two 16B loads at p and p+1024 (global or LDS, conflict-free).

// ---------------- normalize: f32 [N][D] -> fp8 tiled, row L2-normalized ------
__global__ __launch_bounds__(256) void norm4(const float* __restrict__ x0,
                                             const float* __restrict__ x1,
                                             const float* __restrict__ x2,
                                             const float* __restrict__ x3,
                                             unsigned char* __restrict__ o) {
    int a = blockIdx.y;
    const float* x = (a == 0) ? x0 : (a == 1) ? x1 : (a == 2) ? x2 : x3;
    unsigned char* out = o + (size_t)a * N * D;
    int i0 = blockIdx.x * 32;                 // 32-row group
    __shared__ __align__(16) unsigned char tile[24576];
    int t = threadIdx.x, lane = t & 63, w = t >> 6;

    for (int rr = 0; rr < 8; ++rr) {
        int R = i0 + w * 8 + rr;
        const f32x4* xr = (const f32x4*)(x + (size_t)R * D);
        f32x4 v0 = xr[lane * 2], v1 = xr[lane * 2 + 1];
        f32x4 v2 = {}, v3 = {};
        if (lane < 32) { v2 = xr[128 + lane * 2]; v3 = xr[128 + lane * 2 + 1]; }
        float ss = v0[0]*v0[0] + v0[1]*v0[1] + v0[2]*v0[2] + v0[3]*v0[3]
                 + v1[0]*v1[0] + v1[1]*v1[1] + v1[2]*v1[2] + v1[3]*v1[3]
                 + v2[0]*v2[0] + v2[1]*v2[1] + v2[2]*v2[2] + v2[3]*v2[3]
                 + v3[0]*v3[0] + v3[1]*v3[1] + v3[2]*v3[2] + v3[3]*v3[3];
        #pragma unroll
        for (int m = 1; m < 64; m <<= 1) ss += __shfl_xor(ss, m);
        float s = 1.0f / fmaxf(sqrtf(ss), 1e-8f);

        int lrg = (R >> 4) & 1;
        {
            unsigned int wlo = __builtin_amdgcn_cvt_pk_fp8_f32(v0[0]*s, v0[1]*s, 0, false) & 0xffff;
            unsigned int whi = __builtin_amdgcn_cvt_pk_fp8_f32(v0[2]*s, v0[3]*s, 0, false) & 0xffff;
            unsigned int w0 = wlo | (whi << 16);
            wlo = __builtin_amdgcn_cvt_pk_fp8_f32(v1[0]*s, v1[1]*s, 0, false) & 0xffff;
            whi = __builtin_amdgcn_cvt_pk_fp8_f32(v1[2]*s, v1[3]*s, 0, false) & 0xffff;
            unsigned int w1 = wlo | (whi << 16);
            int g = lane;
            int off = (lrg * 6 + (g >> 4)) * 2048 + ((g >> 1) & 1) * 1024
                    + ((R & 15) + 16 * ((g & 15) >> 2)) * 16 + (g & 1) * 8;
            *(uint2*)(tile + off) = make_uint2(w0, w1);
        }
        if (lane < 32) {
            unsigned int wlo = __builtin_amdgcn_cvt_pk_fp8_f32(v2[0]*s, v2[1]*s, 0, false) & 0xffff;
            unsigned int whi = __builtin_amdgcn_cvt_pk_fp8_f32(v2[2]*s, v2[3]*s, 0, false) & 0xffff;
            unsigned int w0 = wlo | (whi << 16);
            wlo = __builtin_amdgcn_cvt_pk_fp8_f32(v3[0]*s, v3[1]*s, 0, false) & 0xffff;
            whi = __builtin_amdgcn_cvt_pk_fp8_f32(v3[2]*s, v3[3]*s, 0, false) & 0xffff;
            unsigned int w1 = wlo | (whi << 16);
            int g = 64 + lane;
            int off = (lrg * 6 + (g >> 4)) * 2048 + ((g >> 1) & 1) * 1024
                    + ((R & 15) + 16 * ((g & 15) >> 2)) * 16 + (g & 1) * 8;
            *(uint2*)(tile + off) = make_uint2(w0, w1);
        }
    }
    __syncthreads();
    unsigned char* dst = out + (size_t)(i0 >> 5) * 24576;
    #pragma unroll
    for (int i = 0; i < 6; ++i)
        ((int4*)dst)[t + i * 256] = ((const int4*)tile)[t + i * 256];
}

// ---------------- one gemm pass: acc += A_blk(128) x B_blk(128)^T ------------
// R7-verified structure: BK=128 chunks, LDS buffer 32KB (A 8 frag-tiles @0,
// B @16384), dbuf 64KB, 2 blocks/CU. Per chunk: ISSUE(c+1) 8 gloads ->
// vmcnt(8) [= exactly c+1's loads left in flight; c fully staged] -> barrier
// -> 16 ds_read_b128 -> 16 MFMA(K=128, scales=1) -> barrier.
__device__ __forceinline__ void gemm_pass(const unsigned char* __restrict__ A,
                                          const unsigned char* __restrict__ B,
                                          char* smem, int ib, int jb, int t,
                                          f32x4 (&acc)[4][4]) {
    const int lane = t & 63, w = t >> 6;
    const int wm = w >> 1, wn = w & 1;

    // staging: wave w covers A frag-tiles {2w, 2w+1}, B frag-tiles {2w, 2w+1}
    const unsigned char* gA = A + (size_t)((ib * 8 + 2 * w) * 6) * 2048 + lane * 16;
    const unsigned char* gB = B + (size_t)((jb * 8 + 2 * w) * 6) * 2048 + lane * 16;
    const int sd = w * 4096 + lane * 16;

    #define ISSUE(c)  do {                                                     \
        char* buf = smem + ((c) & 1) * 32768;                                  \
        const unsigned char* sa = gA + (c) * 2048;                             \
        const unsigned char* sb = gB + (c) * 2048;                             \
        gload16(sa,         buf + sd);                                         \
        gload16(sa + 1024,  buf + sd + 1024);                                  \
        gload16(sa + 12288, buf + sd + 2048);                                  \
        gload16(sa + 13312, buf + sd + 3072);                                  \
        gload16(sb,         buf + 16384 + sd);                                 \
        gload16(sb + 1024,  buf + 16384 + sd + 1024);                          \
        gload16(sb + 12288, buf + 16384 + sd + 2048);                          \
        gload16(sb + 13312, buf + 16384 + sd + 3072);                          \
    } while (0)

    ISSUE(0);

    #pragma unroll 1
    for (int c = 0; c < NC; ++c) {
        if (c < NC - 1) {
            ISSUE(c + 1);
            asm volatile("s_waitcnt vmcnt(8)" ::: "memory");  // c staged, c+1 in flight
        } else {
            asm volatile("s_waitcnt vmcnt(0)" ::: "memory");  // tail: drain all
        }
        __builtin_amdgcn_s_barrier();
        asm volatile("" ::: "memory");

        const char* cb = smem + (c & 1) * 32768;
        union { int4 q[2]; v8i v; } a[4], b[4];
        #pragma unroll
        for (int m = 0; m < 4; ++m) {
            const char* p = cb + (wm * 4 + m) * 2048 + lane * 16;
            a[m].q[0] = *(const int4*)p;
            a[m].q[1] = *(const int4*)(p + 1024);
        }
        #pragma unroll
        for (int n = 0; n < 4; ++n) {
            const char* p = cb + 16384 + (wn * 4 + n) * 2048 + lane * 16;
            b[n].q[0] = *(const int4*)p;
            b[n].q[1] = *(const int4*)(p + 1024);
        }
        __builtin_amdgcn_s_setprio(1);
        #pragma unroll
        for (int m = 0; m < 4; ++m)
            #pragma unroll
            for (int n = 0; n < 4; ++n)
                acc[m][n] = __builtin_amdgcn_mfma_scale_f32_16x16x128_f8f6f4(
                    a[m].v, b[n].v, acc[m][n], 0, 0, 0, 127, 0, 127);
        __builtin_amdgcn_s_setprio(0);
        __builtin_amdgcn_s_barrier();   // all reads of buffer c done
    }
    #undef ISSUE
}

__global__ __launch_bounds__(256, 2) void fused_gemm(
        const unsigned char* __restrict__ Xs, const unsigned char* __restrict__ Ys,
        const unsigned char* __restrict__ Xt, const unsigned char* __restrict__ Yt,
        float* __restrict__ partial) {
    __shared__ __align__(16) char smem[65536];
    const int t = threadIdx.x;
    // 2D XCD partition: xcd = bid&7 (preserve HW round-robin). Each XCD owns
    // an 8-ib x 16-jb sub-grid; local order ib-fastest so each 32-CU round
    // touches A-band (1.57MB) + 4 B-panel-pairs (0.79MB) ~= 2.4MB -> L2-fits.
    const int bid = blockIdx.x;
    const int xcd = bid & 7, loc = bid >> 3;          // loc 0..127
    const int ib = (xcd >> 1) * 8 + (loc & 7);
    const int jb = (xcd & 1) * 16 + (loc >> 3);
    const int i0 = ib * 128;
    const int lane = t & 63, wid = t >> 6;
    const int wm = wid >> 1, wn = wid & 1;

    f32x4 acc_s[4][4] = {};
    f32x4 acc_t[4][4] = {};

    gemm_pass(Xs, Ys, smem, ib, jb, t, acc_s);
    gemm_pass(Xt, Yt, smem, ib, jb, t, acc_t);

    // ---- epilogue (R5-proven): per-row partials over this block's 128 cols --
    __syncthreads();
    float* part = (float*)smem;      // [2 wn][128 rows][4 stats]
    int g = lane >> 4, cl = lane & 15;

    #pragma unroll
    for (int m = 0; m < 4; ++m) {
        float st[4][4];
        #pragma unroll
        for (int r = 0; r < 4; ++r) { st[r][0] = 0.f; st[r][1] = 0.f; st[r][2] = 0.f; st[r][3] = 0.f; }
        #pragma unroll
        for (int n = 0; n < 4; ++n)
            #pragma unroll
            for (int r = 0; r < 4; ++r) {
                float ls = 10.0f * acc_s[m][n][r];
                float lt = 10.0f * acc_t[m][n][r];
                float es = __expf(ls - 10.0f);
                float et = __expf(lt - 10.0f);
                st[r][0] += es;
                st[r][1] += et;
                st[r][2] += es * (ls - lt);
                st[r][3] += et * (lt - ls);
            }
        #pragma unroll
        for (int r = 0; r < 4; ++r)
            #pragma unroll
            for (int s = 0; s < 4; ++s) {
                float v = st[r][s];
                v += __shfl_xor(v, 1);
                v += __shfl_xor(v, 2);
                v += __shfl_xor(v, 4);
                v += __shfl_xor(v, 8);
                st[r][s] = v;
            }
        if (cl == 0) {
            int row = wm * 64 + m * 16 + g * 4;
            #pragma unroll
            for (int r = 0; r < 4; ++r)
                #pragma unroll
                for (int s = 0; s < 4; ++s)
                    part[(wn * 128 + row + r) * 4 + s] = st[r][s];
        }
    }
    __syncthreads();
    #pragma unroll
    for (int q = 0; q < 2; ++q) {
        int idx = t + q * 256;
        int row = idx >> 2, s = idx & 3;
        float v = part[(0 * 128 + row) * 4 + s] + part[(1 * 128 + row) * 4 + s];
        partial[((size_t)jb * N + (i0 + row)) * 4 + s] = v;
    }
}

// ---------------- per-row finalize + block partial sums ----------------------
__global__ __launch_bounds__(256) void reduce_rows(const float* __restrict__ partial,
                                                   float* __restrict__ blocksum) {
    int row = blockIdx.x * 256 + threadIdx.x;
    float zs = 0.f, zt = 0.f, ws = 0.f, wt = 0.f;
    for (int jb = 0; jb < 32; ++jb) {
        const float* p = partial + ((size_t)jb * N + row) * 4;
        zs += p[0]; zt += p[1]; ws += p[2]; wt += p[3];
    }
    float ls_row = wt / zt - logf(zt) + logf(zs);
    float lt_row = ws / zs - logf(zs) + logf(zt);
    #pragma unroll
    for (int m = 1; m < 64; m <<= 1) {
        ls_row += __shfl_xor(ls_row, m);
        lt_row += __shfl_xor(lt_row, m);
    }
    __shared__ float rs[4], rt[4];
    int lane = threadIdx.x & 63, wid = threadIdx.x >> 6;
    if (lane == 0) { rs[wid] = ls_row; rt[wid] = lt_row; }
    __syncthreads();
    if (threadIdx.x == 0) {
        blocksum[blockIdx.x * 2]     = rs[0] + rs[1] + rs[2] + rs[3];
        blocksum[blockIdx.x * 2 + 1] = rt[0] + rt[1] + rt[2] + rt[3];
    }
}

__global__ void final_reduce(const float* __restrict__ blocksum, float* __restrict__ out) {
    float a = 0.f, b = 0.f;
    if (threadIdx.x < 16) { a = blocksum[threadIdx.x * 2]; b = blocksum[threadIdx.x * 2 + 1]; }
    #pragma unroll
    for (int m = 1; m < 16; m <<= 1) { a += __shfl_xor(a, m); b += __shfl_xor(b, m); }
    if (threadIdx.x == 0) {
        const float inv = 1.0f / 16777216.0f;   // 1/N^2
        out[0] = a * inv;
        out[1] = b * inv;
    }
}

extern "C" void kernel_launch(void* const* d_in, const int* in_sizes, int n_in,
                              void* d_out, int out_size, void* d_ws, size_t ws_size,
                              hipStream_t stream) {
    const float* zxs = (const float*)d_in[0];
    const float* zys = (const float*)d_in[1];
    const float* zxt = (const float*)d_in[2];
    const float* zyt = (const float*)d_in[3];

    char* ws = (char*)d_ws;
    const size_t A = (size_t)N * D;                   // bytes per fp8 array
    unsigned char* nb = (unsigned char*)ws;           // 4 normalized fp8 arrays (tiled)
    float* partial  = (float*)(ws + 4 * A);           // [32][N][4] f32 = 2 MB
    float* blocksum = (float*)(ws + 4 * A + (size_t)32 * N * 4 * sizeof(float));

    norm4<<<dim3(N / 32, 4), 256, 0, stream>>>(zxs, zys, zxt, zyt, nb);

    const unsigned char* Xs = nb;
    const unsigned char* Ys = nb + A;
    const unsigned char* Xt = nb + 2 * A;
    const unsigned char* Yt = nb + 3 * A;
    fused_gemm<<<dim3(1024), 256, 0, stream>>>(Xs, Ys, Xt, Yt, partial);

    reduce_rows<<<16, 256, 0, stream>>>(partial, blocksum);
    final_reduce<<<1, 64, 0, stream>>>(blocksum, (float*)d_out);
}